// Round 19
// baseline (156.630 us; speedup 1.0000x reference)
//
#include <hip/hip_runtime.h>
#include <hip/hip_bf16.h>
#include <stdint.h>

#define NB  256     // batch
#define NSP 128     // n_spins
#define DM  768     // d_model
#define KMC 25      // coalitions
#define MROWS (NB*KMC)  // 6400

// workspace layout (bytes), all 256-aligned (ws is 384 MiB)
#define OFF_S    0u          // s bf16 [6400][768]          9,830,400 B
#define OFF_WT   9830400u    // w_v^T bf16 [768][768]       1,179,648 B
#define OFF_N2   11010048u   // norm2 f32 [6400]               25,600 B
#define OFF_COEF 11035648u   // coefT f32 [128][28]            14,336 B
#define OFF_CNT  11049984u   // kB completion counter u32           4 B

typedef __attribute__((ext_vector_type(8))) short bf16x8;
typedef __attribute__((ext_vector_type(4))) float f32x4;
typedef __attribute__((ext_vector_type(16))) float f32x16;
typedef unsigned int u32;

#define GLOAD_LDS16(gp, lp) \
  __builtin_amdgcn_global_load_lds((const __attribute__((address_space(1))) u32*)(gp), \
                                   (__attribute__((address_space(3))) u32*)(lp), 16, 0, 0)

// counted-vmcnt barrier (T4): wait until only the N newest VMEM ops remain.
#define KA_WAITV_BAR(N) asm volatile("s_waitcnt vmcnt(" #N ")\n\ts_barrier" ::: "memory")
#define KA_BAR()        asm volatile("s_barrier" ::: "memory")

#define KACH (16 * 384)   // floats per kA chunk

// ---------------- merged kernel: kA (bid<512) + prep (bid>=512) -------------
__global__ __launch_bounds__(256, 2) void kA_prep(const float* __restrict__ f,
                                                  const int* __restrict__ co,
                                                  const float* __restrict__ wv,
                                                  char* __restrict__ ws) {
  __shared__ __align__(16) char smem[3 * KACH * 4];   // 73,728 B (overlaid)
  const int bid = blockIdx.x;
  const int tid = threadIdx.x;

  if (bid >= 512) {
    const int blk = bid - 512;
    const int t = tid;
    if (blk < 144) {             // 12x12 tiles of 64x64: wT[n][k] = bf16(wv[k][n])
      __hip_bfloat16 (*lt)[66] = (__hip_bfloat16(*)[66])smem;
      const int bi = blk / 12, bj = blk % 12;
      const int k0 = bi * 64, n0 = bj * 64;
      #pragma unroll
      for (int i = 0; i < 16; ++i) {
        int idx = t + i * 256;
        int r = idx >> 6, c = idx & 63;
        lt[c][r] = __float2bfloat16(wv[(size_t)(k0 + r) * DM + n0 + c]);
      }
      __syncthreads();
      __hip_bfloat16* wT = (__hip_bfloat16*)(ws + OFF_WT);
      #pragma unroll
      for (int i = 0; i < 16; ++i) {
        int idx = t + i * 256;
        int r = idx >> 6, c = idx & 63;
        wT[(size_t)(n0 + r) * DM + k0 + c] = lt[r][c];
      }
    } else if (blk == 144) {     // shapley coefficients + kB counter reset
      if (t < NSP) {
        const int n = t;
        int cw = 0;
        #pragma unroll
        for (int k = 0; k < KMC; ++k) cw += co[k * NSP + n];
        const int cwo = KMC - cw;
        const bool valid = (cw > 0) && (cwo > 0);
        float* coefT = (float*)(ws + OFF_COEF);
        #pragma unroll
        for (int k = 0; k < 28; ++k) {
          float v = 0.f;
          if (valid && k < KMC) v = co[k * NSP + n] ? (1.f / (float)cw) : (-1.f / (float)cwo);
          coefT[n * 28 + k] = v;
        }
      } else if (t == NSP) {
        *(u32*)(ws + OFF_CNT) = 0;   // dispatch boundary orders this before kB
      }
    } else {                     // blk 145..169: zero norm2 accumulators
      int i = (blk - 145) * 256 + t;
      if (i < MROWS) ((float*)(ws + OFF_N2))[i] = 0.f;
    }
    return;
  }

  // ---------------- kA body (r15-v10 schedule, r16 co-direct fragments) -----
  const int b = bid >> 1;
  const int half = bid & 1;        // d-half: cols [half*384, half*384+384)
  const int w = tid >> 6;          // 4 waves, 96 d-cols each
  const int lane = tid & 63;
  const int l31 = lane & 31, l5 = lane >> 5;

  float (*Fs)[KACH] = (float(*)[KACH])smem;   // ring-3, 73,728 B
  __hip_bfloat16* s = (__hip_bfloat16*)(ws + OFF_S);

  // A-fragments for all 8 K-steps: row = lane&31, k = ks*16 + l5*8 + j.
  bf16x8 Af[8];
  #pragma unroll
  for (int ks = 0; ks < 8; ++ks) {
    if (l31 < KMC) {
      const int* cp = co + l31 * NSP + ks * 16 + l5 * 8;
      int4 c0 = *(const int4*)(cp);
      int4 c1 = *(const int4*)(cp + 4);
      __hip_bfloat16 h;
      h = __float2bfloat16((float)c0.x); Af[ks][0] = *(short*)&h;
      h = __float2bfloat16((float)c0.y); Af[ks][1] = *(short*)&h;
      h = __float2bfloat16((float)c0.z); Af[ks][2] = *(short*)&h;
      h = __float2bfloat16((float)c0.w); Af[ks][3] = *(short*)&h;
      h = __float2bfloat16((float)c1.x); Af[ks][4] = *(short*)&h;
      h = __float2bfloat16((float)c1.y); Af[ks][5] = *(short*)&h;
      h = __float2bfloat16((float)c1.z); Af[ks][6] = *(short*)&h;
      h = __float2bfloat16((float)c1.w); Af[ks][7] = *(short*)&h;
    } else {
      #pragma unroll
      for (int j = 0; j < 8; ++j) Af[ks][j] = 0;
    }
  }
  asm volatile("s_waitcnt vmcnt(0)" ::: "memory");   // clean vmcnt base

  const float* fb = f + (size_t)b * NSP * DM + half * 384;
  int goff[6];
  #pragma unroll
  for (int q = 0; q < 6; ++q) {
    int e = (w * 6 + q) * 256 + lane * 4;
    int r = e / 384, c = e - r * 384;
    goff[q] = r * DM + c;
  }

  f32x16 ac[3];
  #pragma unroll
  for (int nt = 0; nt < 3; ++nt)
    #pragma unroll
    for (int r = 0; r < 16; ++r) ac[nt][r] = 0.f;

#define KA_ISSUE(ck, bi) { \
    const float* fp_ = fb + (size_t)(ck) * 16 * DM; \
    _Pragma("unroll") for (int q = 0; q < 6; ++q) \
      GLOAD_LDS16(fp_ + goff[q], (char*)&Fs[(bi)][0] + ((w * 6 + q) << 10)); }

#define KA_MFMA(ks, bi) { \
    _Pragma("unroll") for (int nt = 0; nt < 3; ++nt) { \
      bf16x8 Bf; \
      _Pragma("unroll") for (int j = 0; j < 8; ++j) { \
        float v_ = Fs[(bi)][(l5 * 8 + j) * 384 + w * 96 + nt * 32 + l31]; \
        __hip_bfloat16 h_ = __float2bfloat16(v_); \
        Bf[j] = *(short*)&h_; } \
      ac[nt] = __builtin_amdgcn_mfma_f32_32x32x16_bf16(Af[ks], Bf, ac[nt], 0, 0, 0); } }

  KA_ISSUE(0, 0) KA_ISSUE(1, 1) KA_ISSUE(2, 2)   // 18 windows/wave in flight
  KA_WAITV_BAR(12);  KA_MFMA(0, 0)  KA_BAR();  KA_ISSUE(3, 0)
  KA_WAITV_BAR(12);  KA_MFMA(1, 1)  KA_BAR();  KA_ISSUE(4, 1)
  KA_WAITV_BAR(12);  KA_MFMA(2, 2)  KA_BAR();  KA_ISSUE(5, 2)
  KA_WAITV_BAR(12);  KA_MFMA(3, 0)  KA_BAR();  KA_ISSUE(6, 0)
  KA_WAITV_BAR(12);  KA_MFMA(4, 1)  KA_BAR();  KA_ISSUE(7, 1)
  KA_WAITV_BAR(12);  KA_MFMA(5, 2)
  KA_WAITV_BAR(6);   KA_MFMA(6, 0)
  KA_WAITV_BAR(0);   KA_MFMA(7, 1)

#undef KA_ISSUE
#undef KA_MFMA

  // epilogue: D col = lane&31, row = (r&3) + 8*(r>>2) + 4*l5
  #pragma unroll
  for (int nt = 0; nt < 3; ++nt) {
    int dcol = half * 384 + w * 96 + nt * 32 + l31;
    #pragma unroll
    for (int r = 0; r < 16; ++r) {
      int row = (r & 3) + 8 * (r >> 2) + 4 * l5;
      if (row < KMC)
        s[((size_t)b * KMC + row) * DM + dcol] = __float2bfloat16(ac[nt][r]);
    }
  }
}

// ---------------- kernel B: row-norms of s @ wT^T + fused finalize ----------
// v4: BN 192->96 -> grid 800 = 3.1 blocks/CU (TLP hides per-K-step drains).
// LDS packed 20.5 KB; buffer selection via inline pointer arithmetic (no
// pointer arrays -- addrspacecast static-init is unsupported on gfx950).
// Last-finishing block (device counter) performs kC's finalize in-place.
#define BM 64
#define BN 96
#define BK 32
#define NTK 24   // 768/32
#define KB_GRID 800
#define KB_AOFF(bsel) ((bsel) * 4096)
#define KB_BOFF(bsel) (8192 + (bsel) * 6144)

__global__ __launch_bounds__(256) void kB(char* __restrict__ ws,
                                          const float* __restrict__ scale,
                                          float* __restrict__ out) {
  const int bid = blockIdx.x;      // 800 = 100 (M) * 8 (N)
  const int tm = bid >> 3;
  const int tn = bid & 7;
  const int tid = threadIdx.x;
  const int wid = tid >> 6;
  const int lane = tid & 63;
  const int wm = wid >> 1;         // 2x2 wave grid: 32 rows x 48 cols per wave
  const int wn = wid & 1;

  const __hip_bfloat16* S  = (const __hip_bfloat16*)(ws + OFF_S);
  const __hip_bfloat16* WT = (const __hip_bfloat16*)(ws + OFF_WT);
  float* norm2 = (float*)(ws + OFF_N2);

  __shared__ __align__(16) char smemB[2 * 4096 + 2 * 6144];  // 20,480 B

  // staging: global src pre-swizzled (slot ^= (r>>1)&3), LDS dest linear.
  // A: 4 windows (1/wave). B: 6 windows -> wave w takes {w} and {w+4 if w<2}.
  const char* gA;
  {
    int li = wid * 64 + lane;
    int r = li >> 2, sl = li & 3;
    int slx = sl ^ ((r >> 1) & 3);
    gA = (const char*)(S + (size_t)(tm * BM + r) * DM) + slx * 16;
  }
  const char* gB0; const char* gB1;
  {
    int li = wid * 64 + lane;
    int r = li >> 2, sl = li & 3;
    int slx = sl ^ ((r >> 1) & 3);
    gB0 = (const char*)(WT + (size_t)(tn * BN + r) * DM) + slx * 16;
    int j1 = (wid < 2) ? wid + 4 : wid;        // dummy for wid>=2 (not issued)
    int li1 = j1 * 64 + lane;
    int r1 = li1 >> 2, sl1 = li1 & 3;
    int slx1 = sl1 ^ ((r1 >> 1) & 3);
    gB1 = (const char*)(WT + (size_t)(tn * BN + r1) * DM) + slx1 * 16;
  }

  auto stage = [&](int tk, int bsel) {
    size_t koff = (size_t)tk * (BK * 2);   // 64 bytes per K-step
    GLOAD_LDS16(gA + koff, smemB + KB_AOFF(bsel) + wid * 1024);
    GLOAD_LDS16(gB0 + koff, smemB + KB_BOFF(bsel) + wid * 1024);
    if (wid < 2) GLOAD_LDS16(gB1 + koff, smemB + KB_BOFF(bsel) + (wid + 4) * 1024);
  };

  f32x4 acc[2][3];
  #pragma unroll
  for (int m = 0; m < 2; ++m)
    #pragma unroll
    for (int n = 0; n < 3; ++n)
      #pragma unroll
      for (int j = 0; j < 4; ++j) acc[m][n][j] = 0.f;

  // fragment read offsets (swizzled to match stage-source permutation)
  int offA[2], offB[3];
  #pragma unroll
  for (int m = 0; m < 2; ++m) {
    int r = wm * 32 + m * 16 + (lane & 15);
    int sl = (lane >> 4) ^ ((r >> 1) & 3);
    offA[m] = r * 64 + sl * 16;
  }
  #pragma unroll
  for (int n = 0; n < 3; ++n) {
    int r = wn * 48 + n * 16 + (lane & 15);
    int sl = (lane >> 4) ^ ((r >> 1) & 3);
    offB[n] = r * 64 + sl * 16;
  }

  stage(0, 0);
  for (int tk = 0; tk < NTK; ++tk) {
    int cur = tk & 1;
    __syncthreads();               // drains vmcnt(0): staged tile ready
    if (tk + 1 < NTK) stage(tk + 1, cur ^ 1);
    bf16x8 af[2], bfr[3];
    #pragma unroll
    for (int m = 0; m < 2; ++m)
      af[m] = *(const bf16x8*)(smemB + KB_AOFF(cur) + offA[m]);
    #pragma unroll
    for (int n = 0; n < 3; ++n)
      bfr[n] = *(const bf16x8*)(smemB + KB_BOFF(cur) + offB[n]);
    #pragma unroll
    for (int m = 0; m < 2; ++m)
      #pragma unroll
      for (int n = 0; n < 3; ++n)
        acc[m][n] = __builtin_amdgcn_mfma_f32_16x16x32_bf16(af[m], bfr[n], acc[m][n], 0, 0, 0);
  }

  // epilogue: sum of squares over this wave's 48-col slice, reduce 16 lanes,
  // atomicAdd into norm2[row]  (C/D layout: col=lane&15, row=(lane>>4)*4+reg)
  float ps[2][4];
  #pragma unroll
  for (int m = 0; m < 2; ++m)
    #pragma unroll
    for (int i = 0; i < 4; ++i) {
      float v = 0.f;
      #pragma unroll
      for (int n = 0; n < 3; ++n) { float x = acc[m][n][i]; v += x * x; }
      #pragma unroll
      for (int d = 1; d < 16; d <<= 1) v += __shfl_xor(v, d, 64);
      ps[m][i] = v;
    }
  if ((lane & 15) == 0) {
    int g = lane >> 4;
    #pragma unroll
    for (int m = 0; m < 2; ++m)
      #pragma unroll
      for (int i = 0; i < 4; ++i)
        atomicAdd(&norm2[tm * BM + wm * 32 + m * 16 + g * 4 + i], ps[m][i]);
  }

  // ---- last-block finalize (replaces kernel C) ----
  __threadfence();                 // release our norm2 atomics
  __syncthreads();
  __shared__ int lastFlag;
  if (tid == 0) {
    u32 old = atomicAdd((u32*)(ws + OFF_CNT), 1u);
    lastFlag = (old == KB_GRID - 1);
  }
  __syncthreads();
  if (!lastFlag) return;
  __threadfence();                 // acquire: all blocks' norm2 visible

  const float* coefT = (const float*)(ws + OFF_COEF);
  float* cvLds = (float*)smemB;    // re-use staging LDS (5120 floats avail)
  const float scl = scale[0];
  #pragma unroll
  for (int p = 0; p < 2; ++p) {    // two b-halves of 128 (3200 cv each)
    __syncthreads();
    for (int i = tid; i < 128 * KMC; i += 256) {
      float nv = atomicAdd(&norm2[p * 128 * KMC + i], 0.0f);  // coherent read
      cvLds[i] = fmaxf(sqrtf(fmaxf(nv, 0.f)) * scl, 0.f);
    }
    __syncthreads();
    for (int idx = tid; idx < 128 * NSP; idx += 256) {
      int bb = idx >> 7, n = idx & 127;
      const float* cf = coefT + n * 28;
      const float* cv = cvLds + bb * KMC;
      float sum = 0.f;
      #pragma unroll
      for (int k = 0; k < KMC; ++k) sum += cv[k] * cf[k];
      out[(size_t)(p * 128 + bb) * NSP + n] = sum;
    }
  }
}

extern "C" void kernel_launch(void* const* d_in, const int* in_sizes, int n_in,
                              void* d_out, int out_size, void* d_ws, size_t ws_size,
                              hipStream_t stream) {
  const float* features   = (const float*)d_in[0];
  const int*   coalitions = (const int*)d_in[1];
  const float* wv         = (const float*)d_in[2];
  const float* scale      = (const float*)d_in[3];
  char* ws = (char*)d_ws;

  // 682 = 512 kA blocks + 144 wT-transpose + 1 coef/counter + 25 norm2-zero
  kA_prep<<<682, 256, 0, stream>>>(features, coalitions, wv, ws);
  kB<<<KB_GRID, 256, 0, stream>>>(ws, scale, (float*)d_out);
}

// Round 20
// 47.828 us; speedup vs baseline: 3.2748x; 3.2748x over previous
//
#include <hip/hip_runtime.h>
#include <hip/hip_bf16.h>
#include <stdint.h>

#define NB  256     // batch
#define NSP 128     // n_spins
#define DM  768     // d_model
#define KMC 25      // coalitions
#define MROWS (NB*KMC)  // 6400

// workspace layout (bytes), all 256-aligned (ws is 384 MiB)
#define OFF_S    0u          // s bf16 [6400][768]          9,830,400 B
#define OFF_WT   9830400u    // w_v^T bf16 [768][768]       1,179,648 B
#define OFF_N2   11010048u   // norm2 f32 [6400]               25,600 B
#define OFF_COEF 11035648u   // coefT f32 [128][28]            14,336 B

typedef __attribute__((ext_vector_type(8))) short bf16x8;
typedef __attribute__((ext_vector_type(4))) float f32x4;
typedef __attribute__((ext_vector_type(16))) float f32x16;
typedef unsigned int u32;

#define GLOAD_LDS16(gp, lp) \
  __builtin_amdgcn_global_load_lds((const __attribute__((address_space(1))) u32*)(gp), \
                                   (__attribute__((address_space(3))) u32*)(lp), 16, 0, 0)

// counted-vmcnt barrier (T4): wait until only the N newest VMEM ops remain.
#define KA_WAITV_BAR(N) asm volatile("s_waitcnt vmcnt(" #N ")\n\ts_barrier" ::: "memory")
#define KA_BAR()        asm volatile("s_barrier" ::: "memory")

#define KACH (16 * 384)   // floats per kA chunk

// ---------------- merged kernel: kA (bid<512) + prep (bid>=512) -------------
__global__ __launch_bounds__(256, 2) void kA_prep(const float* __restrict__ f,
                                                  const int* __restrict__ co,
                                                  const float* __restrict__ wv,
                                                  char* __restrict__ ws) {
  __shared__ __align__(16) char smem[3 * KACH * 4];   // 73,728 B (overlaid)
  const int bid = blockIdx.x;
  const int tid = threadIdx.x;

  if (bid >= 512) {
    const int blk = bid - 512;
    const int t = tid;
    if (blk < 144) {             // 12x12 tiles of 64x64: wT[n][k] = bf16(wv[k][n])
      __hip_bfloat16 (*lt)[66] = (__hip_bfloat16(*)[66])smem;
      const int bi = blk / 12, bj = blk % 12;
      const int k0 = bi * 64, n0 = bj * 64;
      #pragma unroll
      for (int i = 0; i < 16; ++i) {
        int idx = t + i * 256;
        int r = idx >> 6, c = idx & 63;
        lt[c][r] = __float2bfloat16(wv[(size_t)(k0 + r) * DM + n0 + c]);
      }
      __syncthreads();
      __hip_bfloat16* wT = (__hip_bfloat16*)(ws + OFF_WT);
      #pragma unroll
      for (int i = 0; i < 16; ++i) {
        int idx = t + i * 256;
        int r = idx >> 6, c = idx & 63;
        wT[(size_t)(n0 + r) * DM + k0 + c] = lt[r][c];
      }
    } else if (blk == 144) {     // per-(n,k) shapley coefficients
      if (t < NSP) {
        const int n = t;
        int cw = 0;
        #pragma unroll
        for (int k = 0; k < KMC; ++k) cw += co[k * NSP + n];
        const int cwo = KMC - cw;
        const bool valid = (cw > 0) && (cwo > 0);
        float* coefT = (float*)(ws + OFF_COEF);
        #pragma unroll
        for (int k = 0; k < 28; ++k) {
          float v = 0.f;
          if (valid && k < KMC) v = co[k * NSP + n] ? (1.f / (float)cw) : (-1.f / (float)cwo);
          coefT[n * 28 + k] = v;
        }
      }
    } else {                     // blk 145..169: zero norm2 accumulators
      int i = (blk - 145) * 256 + t;
      if (i < MROWS) ((float*)(ws + OFF_N2))[i] = 0.f;
    }
    return;
  }

  // ---------------- kA body (r15-v10 schedule, r16 co-direct fragments) -----
  const int b = bid >> 1;
  const int half = bid & 1;        // d-half: cols [half*384, half*384+384)
  const int w = tid >> 6;          // 4 waves, 96 d-cols each
  const int lane = tid & 63;
  const int l31 = lane & 31, l5 = lane >> 5;

  float (*Fs)[KACH] = (float(*)[KACH])smem;   // ring-3, 73,728 B
  __hip_bfloat16* s = (__hip_bfloat16*)(ws + OFF_S);

  // A-fragments for all 8 K-steps: row = lane&31, k = ks*16 + l5*8 + j.
  bf16x8 Af[8];
  #pragma unroll
  for (int ks = 0; ks < 8; ++ks) {
    if (l31 < KMC) {
      const int* cp = co + l31 * NSP + ks * 16 + l5 * 8;
      int4 c0 = *(const int4*)(cp);
      int4 c1 = *(const int4*)(cp + 4);
      __hip_bfloat16 h;
      h = __float2bfloat16((float)c0.x); Af[ks][0] = *(short*)&h;
      h = __float2bfloat16((float)c0.y); Af[ks][1] = *(short*)&h;
      h = __float2bfloat16((float)c0.z); Af[ks][2] = *(short*)&h;
      h = __float2bfloat16((float)c0.w); Af[ks][3] = *(short*)&h;
      h = __float2bfloat16((float)c1.x); Af[ks][4] = *(short*)&h;
      h = __float2bfloat16((float)c1.y); Af[ks][5] = *(short*)&h;
      h = __float2bfloat16((float)c1.z); Af[ks][6] = *(short*)&h;
      h = __float2bfloat16((float)c1.w); Af[ks][7] = *(short*)&h;
    } else {
      #pragma unroll
      for (int j = 0; j < 8; ++j) Af[ks][j] = 0;
    }
  }
  asm volatile("s_waitcnt vmcnt(0)" ::: "memory");   // clean vmcnt base

  const float* fb = f + (size_t)b * NSP * DM + half * 384;
  int goff[6];
  #pragma unroll
  for (int q = 0; q < 6; ++q) {
    int e = (w * 6 + q) * 256 + lane * 4;
    int r = e / 384, c = e - r * 384;
    goff[q] = r * DM + c;
  }

  f32x16 ac[3];
  #pragma unroll
  for (int nt = 0; nt < 3; ++nt)
    #pragma unroll
    for (int r = 0; r < 16; ++r) ac[nt][r] = 0.f;

#define KA_ISSUE(ck, bi) { \
    const float* fp_ = fb + (size_t)(ck) * 16 * DM; \
    _Pragma("unroll") for (int q = 0; q < 6; ++q) \
      GLOAD_LDS16(fp_ + goff[q], (char*)&Fs[(bi)][0] + ((w * 6 + q) << 10)); }

#define KA_MFMA(ks, bi) { \
    _Pragma("unroll") for (int nt = 0; nt < 3; ++nt) { \
      bf16x8 Bf; \
      _Pragma("unroll") for (int j = 0; j < 8; ++j) { \
        float v_ = Fs[(bi)][(l5 * 8 + j) * 384 + w * 96 + nt * 32 + l31]; \
        __hip_bfloat16 h_ = __float2bfloat16(v_); \
        Bf[j] = *(short*)&h_; } \
      ac[nt] = __builtin_amdgcn_mfma_f32_32x32x16_bf16(Af[ks], Bf, ac[nt], 0, 0, 0); } }

  KA_ISSUE(0, 0) KA_ISSUE(1, 1) KA_ISSUE(2, 2)   // 18 windows/wave in flight
  KA_WAITV_BAR(12);  KA_MFMA(0, 0)  KA_BAR();  KA_ISSUE(3, 0)
  KA_WAITV_BAR(12);  KA_MFMA(1, 1)  KA_BAR();  KA_ISSUE(4, 1)
  KA_WAITV_BAR(12);  KA_MFMA(2, 2)  KA_BAR();  KA_ISSUE(5, 2)
  KA_WAITV_BAR(12);  KA_MFMA(3, 0)  KA_BAR();  KA_ISSUE(6, 0)
  KA_WAITV_BAR(12);  KA_MFMA(4, 1)  KA_BAR();  KA_ISSUE(7, 1)
  KA_WAITV_BAR(12);  KA_MFMA(5, 2)
  KA_WAITV_BAR(6);   KA_MFMA(6, 0)
  KA_WAITV_BAR(0);   KA_MFMA(7, 1)

#undef KA_ISSUE
#undef KA_MFMA

  // epilogue: D col = lane&31, row = (r&3) + 8*(r>>2) + 4*l5
  #pragma unroll
  for (int nt = 0; nt < 3; ++nt) {
    int dcol = half * 384 + w * 96 + nt * 32 + l31;
    #pragma unroll
    for (int r = 0; r < 16; ++r) {
      int row = (r & 3) + 8 * (r >> 2) + 4 * l5;
      if (row < KMC)
        s[((size_t)b * KMC + row) * DM + dcol] = __float2bfloat16(ac[nt][r]);
    }
  }
}

// ---------------- kernel B: norm2[row] += rowwise |s @ wT^T|^2 (bf16 MFMA) ---
// v5: BN 96, grid 800 = 3.1 blocks/CU (r19's GEMM geometry WITHOUT the fused
// finalize/threadfence -- r19 showed 800 device-scope fences cost ~120us via
// cross-XCD L2 writeback/invalidate storms). atomicAdd epilogue (r17-proven).
#define BM 64
#define BN 96
#define BK 32
#define NTK 24   // 768/32
#define KB_AOFF(bsel) ((bsel) * 4096)
#define KB_BOFF(bsel) (8192 + (bsel) * 6144)

__global__ __launch_bounds__(256) void kB(char* __restrict__ ws) {
  const int bid = blockIdx.x;      // 800 = 100 (M) * 8 (N)
  const int tm = bid >> 3;
  const int tn = bid & 7;
  const int tid = threadIdx.x;
  const int wid = tid >> 6;
  const int lane = tid & 63;
  const int wm = wid >> 1;         // 2x2 wave grid: 32 rows x 48 cols per wave
  const int wn = wid & 1;

  const __hip_bfloat16* S  = (const __hip_bfloat16*)(ws + OFF_S);
  const __hip_bfloat16* WT = (const __hip_bfloat16*)(ws + OFF_WT);
  float* norm2 = (float*)(ws + OFF_N2);

  __shared__ __align__(16) char smemB[2 * 4096 + 2 * 6144];  // 20,480 B

  // staging: global src pre-swizzled (slot ^= (r>>1)&3), LDS dest linear.
  // A: 4 windows (1/wave). B: 6 windows -> wave w takes {w} and {w+4 if w<2}.
  const char* gA;
  {
    int li = wid * 64 + lane;
    int r = li >> 2, sl = li & 3;
    int slx = sl ^ ((r >> 1) & 3);
    gA = (const char*)(S + (size_t)(tm * BM + r) * DM) + slx * 16;
  }
  const char* gB0; const char* gB1;
  {
    int li = wid * 64 + lane;
    int r = li >> 2, sl = li & 3;
    int slx = sl ^ ((r >> 1) & 3);
    gB0 = (const char*)(WT + (size_t)(tn * BN + r) * DM) + slx * 16;
    int j1 = (wid < 2) ? wid + 4 : wid;        // dummy for wid>=2 (not issued)
    int li1 = j1 * 64 + lane;
    int r1 = li1 >> 2, sl1 = li1 & 3;
    int slx1 = sl1 ^ ((r1 >> 1) & 3);
    gB1 = (const char*)(WT + (size_t)(tn * BN + r1) * DM) + slx1 * 16;
  }

  auto stage = [&](int tk, int bsel) {
    size_t koff = (size_t)tk * (BK * 2);   // 64 bytes per K-step
    GLOAD_LDS16(gA + koff, smemB + KB_AOFF(bsel) + wid * 1024);
    GLOAD_LDS16(gB0 + koff, smemB + KB_BOFF(bsel) + wid * 1024);
    if (wid < 2) GLOAD_LDS16(gB1 + koff, smemB + KB_BOFF(bsel) + (wid + 4) * 1024);
  };

  f32x4 acc[2][3];
  #pragma unroll
  for (int m = 0; m < 2; ++m)
    #pragma unroll
    for (int n = 0; n < 3; ++n)
      #pragma unroll
      for (int j = 0; j < 4; ++j) acc[m][n][j] = 0.f;

  // fragment read offsets (swizzled to match stage-source permutation)
  int offA[2], offB[3];
  #pragma unroll
  for (int m = 0; m < 2; ++m) {
    int r = wm * 32 + m * 16 + (lane & 15);
    int sl = (lane >> 4) ^ ((r >> 1) & 3);
    offA[m] = r * 64 + sl * 16;
  }
  #pragma unroll
  for (int n = 0; n < 3; ++n) {
    int r = wn * 48 + n * 16 + (lane & 15);
    int sl = (lane >> 4) ^ ((r >> 1) & 3);
    offB[n] = r * 64 + sl * 16;
  }

  stage(0, 0);
  for (int tk = 0; tk < NTK; ++tk) {
    int cur = tk & 1;
    __syncthreads();               // drains vmcnt(0): staged tile ready
    if (tk + 1 < NTK) stage(tk + 1, cur ^ 1);
    bf16x8 af[2], bfr[3];
    #pragma unroll
    for (int m = 0; m < 2; ++m)
      af[m] = *(const bf16x8*)(smemB + KB_AOFF(cur) + offA[m]);
    #pragma unroll
    for (int n = 0; n < 3; ++n)
      bfr[n] = *(const bf16x8*)(smemB + KB_BOFF(cur) + offB[n]);
    #pragma unroll
    for (int m = 0; m < 2; ++m)
      #pragma unroll
      for (int n = 0; n < 3; ++n)
        acc[m][n] = __builtin_amdgcn_mfma_f32_16x16x32_bf16(af[m], bfr[n], acc[m][n], 0, 0, 0);
  }

  // epilogue: sum of squares over this wave's 48-col slice, reduce 16 lanes,
  // atomicAdd into norm2[row]  (C/D layout: col=lane&15, row=(lane>>4)*4+reg)
  float ps[2][4];
  #pragma unroll
  for (int m = 0; m < 2; ++m)
    #pragma unroll
    for (int i = 0; i < 4; ++i) {
      float v = 0.f;
      #pragma unroll
      for (int n = 0; n < 3; ++n) { float x = acc[m][n][i]; v += x * x; }
      #pragma unroll
      for (int d = 1; d < 16; d <<= 1) v += __shfl_xor(v, d, 64);
      ps[m][i] = v;
    }
  if ((lane & 15) == 0) {
    int g = lane >> 4;
    #pragma unroll
    for (int m = 0; m < 2; ++m)
      #pragma unroll
      for (int i = 0; i < 4; ++i)
        atomicAdd(&norm2[tm * BM + wm * 32 + m * 16 + g * 4 + i], ps[m][i]);
  }
}

// ---------------- kernel C: cv = relu(sqrt(norm2)*scale); shapley ------------
__global__ __launch_bounds__(128) void kC(const char* __restrict__ ws,
                                          const float* __restrict__ scale,
                                          float* __restrict__ out) {
  const int b = blockIdx.x, n = threadIdx.x;
  const float* norm2 = (const float*)(ws + OFF_N2);
  const float* coefT = (const float*)(ws + OFF_COEF);
  __shared__ float cvs[32];
  if (n < KMC) {
    float nv = norm2[b * KMC + n];
    cvs[n] = fmaxf(sqrtf(fmaxf(nv, 0.f)) * scale[0], 0.f);
  } else if (n < 32) {
    cvs[n] = 0.f;
  }
  __syncthreads();
  float sum = 0.f;
  #pragma unroll
  for (int k = 0; k < KMC; ++k) sum += cvs[k] * coefT[n * 28 + k];
  out[b * NSP + n] = sum;
}

extern "C" void kernel_launch(void* const* d_in, const int* in_sizes, int n_in,
                              void* d_out, int out_size, void* d_ws, size_t ws_size,
                              hipStream_t stream) {
  const float* features   = (const float*)d_in[0];
  const int*   coalitions = (const int*)d_in[1];
  const float* wv         = (const float*)d_in[2];
  const float* scale      = (const float*)d_in[3];
  char* ws = (char*)d_ws;

  // 682 = 512 kA blocks + 144 wT-transpose + 1 coef + 25 norm2-zero
  kA_prep<<<682, 256, 0, stream>>>(features, coalitions, wv, ws);
  kB<<<800, 256, 0, stream>>>(ws);
  kC<<<NB, 128, 0, stream>>>(ws, scale, (float*)d_out);
}

// Round 21
// 42.401 us; speedup vs baseline: 3.6941x; 1.1280x over previous
//
#include <hip/hip_runtime.h>
#include <hip/hip_bf16.h>
#include <stdint.h>

#define NB  256     // batch
#define NSP 128     // n_spins
#define DM  768     // d_model
#define KMC 25      // coalitions
#define MROWS (NB*KMC)  // 6400

// workspace layout (bytes), all 256-aligned (ws is 384 MiB)
#define OFF_S    0u          // s bf16 [6400][768]          9,830,400 B
#define OFF_WT   9830400u    // w_v^T bf16 [768][768]       1,179,648 B
#define OFF_N2   11010048u   // norm2 f32 [6400]               25,600 B
#define OFF_COEF 11035648u   // coefT f32 [128][28]            14,336 B

typedef __attribute__((ext_vector_type(8))) short bf16x8;
typedef __attribute__((ext_vector_type(4))) float f32x4;
typedef __attribute__((ext_vector_type(16))) float f32x16;
typedef unsigned int u32;

#define GLOAD_LDS16(gp, lp) \
  __builtin_amdgcn_global_load_lds((const __attribute__((address_space(1))) u32*)(gp), \
                                   (__attribute__((address_space(3))) u32*)(lp), 16, 0, 0)

// counted-vmcnt barrier (T4): wait until only the N newest VMEM ops remain.
#define KA_WAITV_BAR(N) asm volatile("s_waitcnt vmcnt(" #N ")\n\ts_barrier" ::: "memory")
#define KA_BAR()        asm volatile("s_barrier" ::: "memory")

#define KACH (16 * 384)   // floats per kA chunk

// ---------------- merged kernel: kA (bid<512) + prep (bid>=512) -------------
__global__ __launch_bounds__(256, 2) void kA_prep(const float* __restrict__ f,
                                                  const int* __restrict__ co,
                                                  const float* __restrict__ wv,
                                                  char* __restrict__ ws) {
  __shared__ __align__(16) char smem[3 * KACH * 4];   // 73,728 B (overlaid)
  const int bid = blockIdx.x;
  const int tid = threadIdx.x;

  if (bid >= 512) {
    const int blk = bid - 512;
    const int t = tid;
    if (blk < 144) {             // 12x12 tiles of 64x64: wT[n][k] = bf16(wv[k][n])
      __hip_bfloat16 (*lt)[66] = (__hip_bfloat16(*)[66])smem;
      const int bi = blk / 12, bj = blk % 12;
      const int k0 = bi * 64, n0 = bj * 64;
      #pragma unroll
      for (int i = 0; i < 16; ++i) {
        int idx = t + i * 256;
        int r = idx >> 6, c = idx & 63;
        lt[c][r] = __float2bfloat16(wv[(size_t)(k0 + r) * DM + n0 + c]);
      }
      __syncthreads();
      __hip_bfloat16* wT = (__hip_bfloat16*)(ws + OFF_WT);
      #pragma unroll
      for (int i = 0; i < 16; ++i) {
        int idx = t + i * 256;
        int r = idx >> 6, c = idx & 63;
        wT[(size_t)(n0 + r) * DM + k0 + c] = lt[r][c];
      }
    } else if (blk == 144) {     // per-(n,k) shapley coefficients
      if (t < NSP) {
        const int n = t;
        int cw = 0;
        #pragma unroll
        for (int k = 0; k < KMC; ++k) cw += co[k * NSP + n];
        const int cwo = KMC - cw;
        const bool valid = (cw > 0) && (cwo > 0);
        float* coefT = (float*)(ws + OFF_COEF);
        #pragma unroll
        for (int k = 0; k < 28; ++k) {
          float v = 0.f;
          if (valid && k < KMC) v = co[k * NSP + n] ? (1.f / (float)cw) : (-1.f / (float)cwo);
          coefT[n * 28 + k] = v;
        }
      }
    } else {                     // blk 145..169: zero norm2 accumulators
      int i = (blk - 145) * 256 + t;
      if (i < MROWS) ((float*)(ws + OFF_N2))[i] = 0.f;
    }
    return;
  }

  // ---------------- kA body (r15-v10 schedule, r16 co-direct fragments) -----
  const int b = bid >> 1;
  const int half = bid & 1;        // d-half: cols [half*384, half*384+384)
  const int w = tid >> 6;          // 4 waves, 96 d-cols each
  const int lane = tid & 63;
  const int l31 = lane & 31, l5 = lane >> 5;

  float (*Fs)[KACH] = (float(*)[KACH])smem;   // ring-3, 73,728 B
  __hip_bfloat16* s = (__hip_bfloat16*)(ws + OFF_S);

  // A-fragments for all 8 K-steps: row = lane&31, k = ks*16 + l5*8 + j.
  bf16x8 Af[8];
  #pragma unroll
  for (int ks = 0; ks < 8; ++ks) {
    if (l31 < KMC) {
      const int* cp = co + l31 * NSP + ks * 16 + l5 * 8;
      int4 c0 = *(const int4*)(cp);
      int4 c1 = *(const int4*)(cp + 4);
      __hip_bfloat16 h;
      h = __float2bfloat16((float)c0.x); Af[ks][0] = *(short*)&h;
      h = __float2bfloat16((float)c0.y); Af[ks][1] = *(short*)&h;
      h = __float2bfloat16((float)c0.z); Af[ks][2] = *(short*)&h;
      h = __float2bfloat16((float)c0.w); Af[ks][3] = *(short*)&h;
      h = __float2bfloat16((float)c1.x); Af[ks][4] = *(short*)&h;
      h = __float2bfloat16((float)c1.y); Af[ks][5] = *(short*)&h;
      h = __float2bfloat16((float)c1.z); Af[ks][6] = *(short*)&h;
      h = __float2bfloat16((float)c1.w); Af[ks][7] = *(short*)&h;
    } else {
      #pragma unroll
      for (int j = 0; j < 8; ++j) Af[ks][j] = 0;
    }
  }
  asm volatile("s_waitcnt vmcnt(0)" ::: "memory");   // clean vmcnt base

  const float* fb = f + (size_t)b * NSP * DM + half * 384;
  int goff[6];
  #pragma unroll
  for (int q = 0; q < 6; ++q) {
    int e = (w * 6 + q) * 256 + lane * 4;
    int r = e / 384, c = e - r * 384;
    goff[q] = r * DM + c;
  }

  f32x16 ac[3];
  #pragma unroll
  for (int nt = 0; nt < 3; ++nt)
    #pragma unroll
    for (int r = 0; r < 16; ++r) ac[nt][r] = 0.f;

#define KA_ISSUE(ck, bi) { \
    const float* fp_ = fb + (size_t)(ck) * 16 * DM; \
    _Pragma("unroll") for (int q = 0; q < 6; ++q) \
      GLOAD_LDS16(fp_ + goff[q], (char*)&Fs[(bi)][0] + ((w * 6 + q) << 10)); }

#define KA_MFMA(ks, bi) { \
    _Pragma("unroll") for (int nt = 0; nt < 3; ++nt) { \
      bf16x8 Bf; \
      _Pragma("unroll") for (int j = 0; j < 8; ++j) { \
        float v_ = Fs[(bi)][(l5 * 8 + j) * 384 + w * 96 + nt * 32 + l31]; \
        __hip_bfloat16 h_ = __float2bfloat16(v_); \
        Bf[j] = *(short*)&h_; } \
      ac[nt] = __builtin_amdgcn_mfma_f32_32x32x16_bf16(Af[ks], Bf, ac[nt], 0, 0, 0); } }

  KA_ISSUE(0, 0) KA_ISSUE(1, 1) KA_ISSUE(2, 2)   // 18 windows/wave in flight
  KA_WAITV_BAR(12);  KA_MFMA(0, 0)  KA_BAR();  KA_ISSUE(3, 0)
  KA_WAITV_BAR(12);  KA_MFMA(1, 1)  KA_BAR();  KA_ISSUE(4, 1)
  KA_WAITV_BAR(12);  KA_MFMA(2, 2)  KA_BAR();  KA_ISSUE(5, 2)
  KA_WAITV_BAR(12);  KA_MFMA(3, 0)  KA_BAR();  KA_ISSUE(6, 0)
  KA_WAITV_BAR(12);  KA_MFMA(4, 1)  KA_BAR();  KA_ISSUE(7, 1)
  KA_WAITV_BAR(12);  KA_MFMA(5, 2)
  KA_WAITV_BAR(6);   KA_MFMA(6, 0)
  KA_WAITV_BAR(0);   KA_MFMA(7, 1)

#undef KA_ISSUE
#undef KA_MFMA

  // epilogue: D col = lane&31, row = (r&3) + 8*(r>>2) + 4*l5
  #pragma unroll
  for (int nt = 0; nt < 3; ++nt) {
    int dcol = half * 384 + w * 96 + nt * 32 + l31;
    #pragma unroll
    for (int r = 0; r < 16; ++r) {
      int row = (r & 3) + 8 * (r >> 2) + 4 * l5;
      if (row < KMC)
        s[((size_t)b * KMC + row) * DM + dcol] = __float2bfloat16(ac[nt][r]);
    }
  }
}

// ---------------- kernel B: norm2[row] += rowwise |s @ wT^T|^2 (bf16 MFMA) ---
// r17-proven geometry (BM64/BN192/grid400, 2-buffer, 32 KB LDS) + T1 XCD
// swizzle: grid 400 = 8 XCDs x 50 -> remap so each XCD owns a contiguous
// chunk of logical blocks; a tm-group's 4 N-siblings (sharing one 98 KB
// S-slice) then hit the SAME XCD L2. r20's BN96/grid800 doubled S re-reads
// across XCDs (+5us) -- reverted.
#define BM 64
#define BN 192
#define BK 32
#define NTK 24   // 768/32

__global__ __launch_bounds__(256) void kB(char* __restrict__ ws) {
  const int hwbid = blockIdx.x;    // 400 = 8 * 50, exact -> bijective remap
  const int bid = (hwbid & 7) * 50 + (hwbid >> 3);
  const int tm = bid >> 2;
  const int tn = bid & 3;
  const int tid = threadIdx.x;
  const int wid = tid >> 6;
  const int lane = tid & 63;
  const int wm = wid >> 1;         // 2x2 wave grid: 32 rows x 96 cols per wave
  const int wn = wid & 1;

  const __hip_bfloat16* S  = (const __hip_bfloat16*)(ws + OFF_S);
  const __hip_bfloat16* WT = (const __hip_bfloat16*)(ws + OFF_WT);
  float* norm2 = (float*)(ws + OFF_N2);

  __shared__ __align__(16) char As[2][BM * BK * 2];  // [64][32] bf16, 64B rows
  __shared__ __align__(16) char Bs[2][BN * BK * 2];  // [192][32] bf16, 64B rows

  // staging: global src pre-swizzled (slot ^= (r>>1)&3), LDS dest linear
  const char* gA; char *lAA0, *lAA1;
  {
    int li = wid * 64 + lane;
    int r = li >> 2, sl = li & 3;
    int slx = sl ^ ((r >> 1) & 3);
    gA = (const char*)(S + (size_t)(tm * BM + r) * DM) + slx * 16;
    lAA0 = As[0] + wid * 1024;
    lAA1 = As[1] + wid * 1024;
  }
  const char* gB[3]; char *lB0[3], *lB1[3];
  #pragma unroll
  for (int j = 0; j < 3; ++j) {
    int li = (wid * 3 + j) * 64 + lane;
    int r = li >> 2, sl = li & 3;
    int slx = sl ^ ((r >> 1) & 3);
    gB[j] = (const char*)(WT + (size_t)(tn * BN + r) * DM) + slx * 16;
    lB0[j] = Bs[0] + (wid * 3 + j) * 1024;
    lB1[j] = Bs[1] + (wid * 3 + j) * 1024;
  }

  auto stage = [&](int tk, int bsel) {
    size_t koff = (size_t)tk * (BK * 2);   // 64 bytes per K-step
    GLOAD_LDS16(gA + koff, bsel ? lAA1 : lAA0);
    #pragma unroll
    for (int j = 0; j < 3; ++j) GLOAD_LDS16(gB[j] + koff, bsel ? lB1[j] : lB0[j]);
  };

  f32x4 acc[2][6];
  #pragma unroll
  for (int m = 0; m < 2; ++m)
    #pragma unroll
    for (int n = 0; n < 6; ++n)
      #pragma unroll
      for (int j = 0; j < 4; ++j) acc[m][n][j] = 0.f;

  // fragment read offsets (swizzled to match stage-source permutation)
  int offA[2], offB[6];
  #pragma unroll
  for (int m = 0; m < 2; ++m) {
    int r = wm * 32 + m * 16 + (lane & 15);
    int sl = (lane >> 4) ^ ((r >> 1) & 3);
    offA[m] = r * 64 + sl * 16;
  }
  #pragma unroll
  for (int n = 0; n < 6; ++n) {
    int r = wn * 96 + n * 16 + (lane & 15);
    int sl = (lane >> 4) ^ ((r >> 1) & 3);
    offB[n] = r * 64 + sl * 16;
  }

  stage(0, 0);
  for (int tk = 0; tk < NTK; ++tk) {
    int cur = tk & 1;
    __syncthreads();               // drains vmcnt(0): staged tile ready
    if (tk + 1 < NTK) stage(tk + 1, cur ^ 1);
    bf16x8 af[2], bfr[6];
    #pragma unroll
    for (int m = 0; m < 2; ++m) af[m] = *(const bf16x8*)(As[cur] + offA[m]);
    #pragma unroll
    for (int n = 0; n < 6; ++n) bfr[n] = *(const bf16x8*)(Bs[cur] + offB[n]);
    #pragma unroll
    for (int m = 0; m < 2; ++m)
      #pragma unroll
      for (int n = 0; n < 6; ++n)
        acc[m][n] = __builtin_amdgcn_mfma_f32_16x16x32_bf16(af[m], bfr[n], acc[m][n], 0, 0, 0);
  }

  // epilogue: sum of squares over this block's 96-col slice, reduce 16 lanes,
  // atomicAdd into norm2[row]  (C/D layout: col=lane&15, row=(lane>>4)*4+reg)
  float ps[2][4];
  #pragma unroll
  for (int m = 0; m < 2; ++m)
    #pragma unroll
    for (int i = 0; i < 4; ++i) {
      float v = 0.f;
      #pragma unroll
      for (int n = 0; n < 6; ++n) { float x = acc[m][n][i]; v += x * x; }
      #pragma unroll
      for (int d = 1; d < 16; d <<= 1) v += __shfl_xor(v, d, 64);
      ps[m][i] = v;
    }
  if ((lane & 15) == 0) {
    int g = lane >> 4;
    #pragma unroll
    for (int m = 0; m < 2; ++m)
      #pragma unroll
      for (int i = 0; i < 4; ++i)
        atomicAdd(&norm2[tm * BM + wm * 32 + m * 16 + g * 4 + i], ps[m][i]);
  }
}

// ---------------- kernel C: cv = relu(sqrt(norm2)*scale); shapley ------------
__global__ __launch_bounds__(128) void kC(const char* __restrict__ ws,
                                          const float* __restrict__ scale,
                                          float* __restrict__ out) {
  const int b = blockIdx.x, n = threadIdx.x;
  const float* norm2 = (const float*)(ws + OFF_N2);
  const float* coefT = (const float*)(ws + OFF_COEF);
  __shared__ float cvs[32];
  if (n < KMC) {
    float nv = norm2[b * KMC + n];
    cvs[n] = fmaxf(sqrtf(fmaxf(nv, 0.f)) * scale[0], 0.f);
  } else if (n < 32) {
    cvs[n] = 0.f;
  }
  __syncthreads();
  float sum = 0.f;
  #pragma unroll
  for (int k = 0; k < KMC; ++k) sum += cvs[k] * coefT[n * 28 + k];
  out[b * NSP + n] = sum;
}

extern "C" void kernel_launch(void* const* d_in, const int* in_sizes, int n_in,
                              void* d_out, int out_size, void* d_ws, size_t ws_size,
                              hipStream_t stream) {
  const float* features   = (const float*)d_in[0];
  const int*   coalitions = (const int*)d_in[1];
  const float* wv         = (const float*)d_in[2];
  const float* scale      = (const float*)d_in[3];
  char* ws = (char*)d_ws;

  // 682 = 512 kA blocks + 144 wT-transpose + 1 coef + 25 norm2-zero
  kA_prep<<<682, 256, 0, stream>>>(features, coalitions, wv, ws);
  kB<<<400, 256, 0, stream>>>(ws);
  kC<<<NB, 128, 0, stream>>>(ws, scale, (float*)d_out);
}